// Round 1
// baseline (169.732 us; speedup 1.0000x reference)
//
#include <hip/hip_runtime.h>

// GeoCyclicPadding: x (B=2, C=192, H=360, W=720) f32, p=3
// out (B, C, H+2p=366, W+2p=726):
//   cp[..., wp]   = x[..., (wp - p) mod W]
//   middle rows ho in [p, p+H): out = cp[b,c,ho-p,wp]
//   top rows    ho in [0, p):   out = rolled[b,c, p-1-ho, wp]
//   bottom rows ho >= p+H:      out = rolled[b,c, 2H+p-1-ho, wp]
// where rolled[..., wp] = cp[..., (wp + W/2) mod (W+2p)]
// All cases reduce to: wr = wp (middle) or (wp + W/2) mod Wp (halo);
//                      w  = (wr - p) mod W.

__global__ __launch_bounds__(256) void geo_pad_kernel(const float* __restrict__ x,
                                                      float* __restrict__ out,
                                                      int nvec) {
    constexpr int W  = 720;
    constexpr int H  = 360;
    constexpr int p  = 3;
    constexpr int Wp = W + 2 * p;   // 726
    constexpr int Hp = H + 2 * p;   // 366

    const int stride = gridDim.x * blockDim.x;
    for (int t = blockIdx.x * blockDim.x + threadIdx.x; t < nvec; t += stride) {
        const int idx = t * 4;              // flat output float index
        int wp = idx % Wp;
        int r  = idx / Wp;
        int ho = r % Hp;
        int bc = r / Hp;

        float4 v;
        float* vp = &v.x;
#pragma unroll
        for (int k = 0; k < 4; ++k) {
            int h, wr;
            if (ho >= p && ho < p + H) {    // middle: plain cp
                h  = ho - p;
                wr = wp;
            } else {                        // halo rows: rolled by W/2
                h  = (ho < p) ? (p - 1 - ho) : (2 * H + p - 1 - ho);
                wr = wp + W / 2;
                if (wr >= Wp) wr -= Wp;
            }
            int w = wr - p;
            if (w < 0)       w += W;
            else if (w >= W) w -= W;

            vp[k] = x[(bc * H + h) * W + w];

            // advance (wp, ho, bc) by one output element
            ++wp;
            if (wp == Wp) {
                wp = 0;
                ++ho;
                if (ho == Hp) { ho = 0; ++bc; }
            }
        }
        reinterpret_cast<float4*>(out)[t] = v;
    }
}

extern "C" void kernel_launch(void* const* d_in, const int* in_sizes, int n_in,
                              void* d_out, int out_size, void* d_ws, size_t ws_size,
                              hipStream_t stream) {
    const float* x = (const float*)d_in[0];
    float* out = (float*)d_out;

    const int nvec = out_size / 4;          // 25,508,736 float4 stores
    const int block = 256;
    int grid = (nvec + block - 1) / block;
    const int max_grid = 256 * 8;           // 8 blocks/CU, grid-stride the rest
    if (grid > max_grid) grid = max_grid;

    geo_pad_kernel<<<grid, block, 0, stream>>>(x, out, nvec);
}